// Round 5
// baseline (4425.122 us; speedup 1.0000x reference)
//
#include <hip/hip_runtime.h>

#define T_STEPS 512
#define BATCH 64
#define FDIM 256
#define HDIM 1024
#define CDIM 257

typedef __attribute__((ext_vector_type(8))) short short8;
typedef __attribute__((ext_vector_type(4))) short short4_t;
typedef __attribute__((ext_vector_type(4))) float float4_t;
typedef __attribute__((ext_vector_type(2))) int int2_t;

__device__ __forceinline__ short f2bf(float f) {
  unsigned u = __builtin_bit_cast(unsigned, f);
  unsigned r = (u + 0x7fffu + ((u >> 16) & 1u)) >> 16;   // RNE
  return (short)(r & 0xffffu);
}

__device__ __forceinline__ float sigmoid_f(float x) {
  return 1.0f / (1.0f + __expf(-x));
}
__device__ __forceinline__ float tanh_f(float x) {
  float s = __expf(-2.0f * fabsf(x));
  float t = (1.0f - s) / (1.0f + s);
  return (x < 0.0f) ? -t : t;
}

// 8 x 16B CACHEABLE loads from base + ktl*64B, one waitcnt.
// Freshness is guaranteed by the per-step system acquire fence (buffer_inv)
// executed after the flag poll: stale L1/L2 copies are invalidated, the
// first reader per XCD refetches from LIC, subsequent readers hit L2.
__device__ __forceinline__ void load_h_frags(const short* base, short8 (&bh)[8]) {
  float4_t r0, r1, r2, r3, r4, r5, r6, r7;
  asm volatile(
    "global_load_dwordx4 %0, %8, off\n\t"
    "global_load_dwordx4 %1, %8, off offset:64\n\t"
    "global_load_dwordx4 %2, %8, off offset:128\n\t"
    "global_load_dwordx4 %3, %8, off offset:192\n\t"
    "global_load_dwordx4 %4, %8, off offset:256\n\t"
    "global_load_dwordx4 %5, %8, off offset:320\n\t"
    "global_load_dwordx4 %6, %8, off offset:384\n\t"
    "global_load_dwordx4 %7, %8, off offset:448\n\t"
    "s_waitcnt vmcnt(0)"
    : "=&v"(r0), "=&v"(r1), "=&v"(r2), "=&v"(r3),
      "=&v"(r4), "=&v"(r5), "=&v"(r6), "=&v"(r7)
    : "v"(base)
    : "memory");
  bh[0] = __builtin_bit_cast(short8, r0);
  bh[1] = __builtin_bit_cast(short8, r1);
  bh[2] = __builtin_bit_cast(short8, r2);
  bh[3] = __builtin_bit_cast(short8, r3);
  bh[4] = __builtin_bit_cast(short8, r4);
  bh[5] = __builtin_bit_cast(short8, r5);
  bh[6] = __builtin_bit_cast(short8, r6);
  bh[7] = __builtin_bit_cast(short8, r7);
}

// ---------------------------------------------------------------------------
// prep: fco fp32 -> bf16 (padded to 272 rows), zero h double-buffer + flags
// grid: 272 x 256  (identical to the proven round-0 kernel)
// ---------------------------------------------------------------------------
__global__ void prep_kernel(const float* __restrict__ fco_w,
                            short* __restrict__ fcob,
                            short* __restrict__ hbuf,
                            unsigned* __restrict__ flg)
{
  const int tid = blockIdx.x * 256 + threadIdx.x;
  {
    const int idx = tid * 4;
    const int c = idx >> 10, k = idx & 1023;
    short4_t o;
    if (c < CDIM) {
      const float4_t f = *(const float4_t*)(fco_w + c * HDIM + k);
      o[0] = f2bf(f[0]); o[1] = f2bf(f[1]); o[2] = f2bf(f[2]); o[3] = f2bf(f[3]);
    } else {
      o[0] = 0; o[1] = 0; o[2] = 0; o[3] = 0;
    }
    *(short4_t*)(fcob + idx) = o;
  }
  if (tid < 16384) {   // 2*64*1024 shorts / 8
    short8 z = (short8){0,0,0,0,0,0,0,0};
    *(short8*)(hbuf + tid * 8) = z;
  }
  if (tid < 4096) flg[tid] = 0;   // 256 flags x 16-dword pad
}

// ---------------------------------------------------------------------------
// persistent LSTM kernel: 256 WGs = 64 col-groups x 4 batch-quarters,
// 256 threads (4 waves). Wave w owns K-chunk w (256 of 1024) for all 4 gates.
// Weights live in registers as MFMA A-frags. One __syncthreads per step.
// Cross-WG sync: per-producer monotone flag (own 64B line, round-0 proven).
//
// THE ONLY change vs round 0: h(t-1) consumer loads are CACHEABLE, preceded
// by a per-step system acquire fence (buffer_inv sc0 sc1) after the flag
// poll. This lets each XCD's L2 absorb the 64x-redundant h broadcast
// (8 MB/step of LIC-bypass reads -> ~1 MB/step of LIC fills), attacking the
// measured 2 TB/s LIC saturation. hs history stores are write-through so no
// dirty vector lines exist during the kernel.
// ---------------------------------------------------------------------------
__global__ __launch_bounds__(256, 1) void lstm_kernel(
    const float* __restrict__ x,
    const float* __restrict__ wfx, const float* __restrict__ wix,
    const float* __restrict__ wox, const float* __restrict__ wcx,
    const float* __restrict__ bfx, const float* __restrict__ bix,
    const float* __restrict__ box, const float* __restrict__ bcx,
    const float* __restrict__ wfh, const float* __restrict__ wih,
    const float* __restrict__ woh, const float* __restrict__ wch,
    short* __restrict__ hs, short* __restrict__ hbuf,
    unsigned* __restrict__ flg)
{
  const int tid  = threadIdx.x;
  const int lane = tid & 63;
  const int w    = tid >> 6;      // wave id == K-chunk id
  const int quad = lane >> 4;
  const int lm   = lane & 15;
  const int cg   = blockIdx.x & 63;   // column group (16 h-cols)
  const int bq   = blockIdx.x >> 6;   // batch quarter (16 rows)

  // zbuf[parity][slot = w*4+g][b(16) stride 20][i-quad 4]  (fp32, b128-aligned)
  __shared__ float zbuf[2][16 * 320];

  const float* Wh[4] = {wfh, wih, woh, wch};
  const float* Wx[4] = {wfx, wix, wox, wcx};
  const float* Bx[4] = {bfx, bix, box, bcx};

  // ---- preload weight A-fragments (bf16), K-split by wave ----
  short8 wr[4][8];   // recurrent: gate g, local k-tile (global kt = w*8+ktl)
  short8 wxf[4][2];  // input proj: gate g, local k-tile (global kt2 = w*2+ktl)
#pragma unroll
  for (int g = 0; g < 4; ++g) {
    const float* rw = Wh[g] + (cg * 16 + lm) * HDIM;
#pragma unroll
    for (int ktl = 0; ktl < 8; ++ktl) {
      const float* pk = rw + (w * 8 + ktl) * 32 + quad * 8;
      short8 a;
#pragma unroll
      for (int j = 0; j < 8; ++j) a[j] = f2bf(pk[j]);
      wr[g][ktl] = a;
    }
    const float* rx = Wx[g] + (cg * 16 + lm) * FDIM;
#pragma unroll
    for (int ktl = 0; ktl < 2; ++ktl) {
      const float* pk = rx + (w * 2 + ktl) * 32 + quad * 8;
      short8 a;
#pragma unroll
      for (int j = 0; j < 8; ++j) a[j] = f2bf(pk[j]);
      wxf[g][ktl] = a;
    }
  }

  // wave0 epilogue state: bias per (g, i4*4+r) and cell state (4 cells/lane)
  float4_t biasv[4];
  float cst[4] = {0.f, 0.f, 0.f, 0.f};
  {
    const int i4 = lane >> 4;
#pragma unroll
    for (int g = 0; g < 4; ++g) {
#pragma unroll
      for (int r = 0; r < 4; ++r)
        biasv[g][r] = Bx[g][cg * 16 + i4 * 4 + r];
    }
  }

  // flag this wave polls: producers of K-chunk w at this bq (16 of them),
  // one per lane 0..15 (lanes 16+ duplicate lane lm).
  unsigned* myf   = flg + ((bq * 4 + w) * 16 + lm) * 16;
  // flag this WG produces (own 64B line)
  unsigned* prodf = flg + ((bq * 4 + (cg >> 4)) * 16 + (cg & 15)) * 16;

  for (int t = 0; t < T_STEPS; ++t) {
    const int p = t & 1;

    // ---- x projection: fully off the critical path (no h dependency) ----
    float4_t xf[2][2];
    {
      const float* xb = x + ((t * BATCH) + bq * 16 + lm) * FDIM;
#pragma unroll
      for (int i = 0; i < 2; ++i) {
        const float* pk = xb + (w * 2 + i) * 32 + quad * 8;
        xf[i][0] = *(const float4_t*)(pk);
        xf[i][1] = *(const float4_t*)(pk + 4);
      }
    }
    short8 bx[2];
#pragma unroll
    for (int i = 0; i < 2; ++i) {
      short8 a;
      a[0] = f2bf(xf[i][0][0]); a[1] = f2bf(xf[i][0][1]);
      a[2] = f2bf(xf[i][0][2]); a[3] = f2bf(xf[i][0][3]);
      a[4] = f2bf(xf[i][1][0]); a[5] = f2bf(xf[i][1][1]);
      a[6] = f2bf(xf[i][1][2]); a[7] = f2bf(xf[i][1][3]);
      bx[i] = a;
    }
    float4_t acc[4];
#pragma unroll
    for (int g = 0; g < 4; ++g) acc[g] = (float4_t){0.f, 0.f, 0.f, 0.f};
#pragma unroll
    for (int i = 0; i < 2; ++i) {
#pragma unroll
      for (int g = 0; g < 4; ++g)
        acc[g] = __builtin_amdgcn_mfma_f32_16x16x32_bf16(wxf[g][i], bx[i], acc[g], 0, 0, 0);
    }

    // ---- wait for the 16 producers of our K-chunk to publish h(t-1) ----
    {
      const unsigned want = (unsigned)t;
      unsigned v;
      do {
        v = __hip_atomic_load(myf, __ATOMIC_RELAXED, __HIP_MEMORY_SCOPE_SYSTEM);
      } while (__all((int)(v >= want)) == 0);
    }

    // ---- acquire: invalidate stale L1/L2 copies, then CACHED h loads ----
    __builtin_amdgcn_fence(__ATOMIC_ACQUIRE, "");
    short8 bh[8];
    load_h_frags(hbuf + (p ^ 1) * (BATCH * HDIM) + (bq * 16 + lm) * HDIM
                      + w * 256 + quad * 8, bh);

#pragma unroll
    for (int ktl = 0; ktl < 8; ++ktl) {
#pragma unroll
      for (int g = 0; g < 4; ++g)
        acc[g] = __builtin_amdgcn_mfma_f32_16x16x32_bf16(wr[g][ktl], bh[ktl], acc[g], 0, 0, 0);
    }

    // partial z (K-chunk) -> LDS. D rows = quad*4+r (i), cols = lm (b).
#pragma unroll
    for (int g = 0; g < 4; ++g)
      *(float4_t*)(&zbuf[p][(w * 4 + g) * 320 + lm * 20 + quad * 4]) = acc[g];

    __syncthreads();

    if (w == 0) {
      const int b = lane & 15, i4 = lane >> 4;   // cell (i = i4*4+r, b)
      const float* zb = &zbuf[p][b * 20 + i4 * 4];
      float4_t zs[4];
#pragma unroll
      for (int g = 0; g < 4; ++g) {
        float4_t v0 = *(const float4_t*)(zb + (0  + g) * 320);
        float4_t v1 = *(const float4_t*)(zb + (4  + g) * 320);
        float4_t v2 = *(const float4_t*)(zb + (8  + g) * 320);
        float4_t v3 = *(const float4_t*)(zb + (12 + g) * 320);
        zs[g] = (v0 + v1) + (v2 + v3) + biasv[g];
      }
      short4_t hv;
#pragma unroll
      for (int r = 0; r < 4; ++r) {
        float ff = sigmoid_f(zs[0][r]);
        float ii = sigmoid_f(zs[1][r]);
        float oo = sigmoid_f(zs[2][r]);
        float aa = tanh_f(zs[3][r]);
        float cn = ii * aa + ff * cst[r];
        cst[r] = cn;
        hv[r] = f2bf(oo * tanh_f(cn));
      }
      const int bg  = bq * 16 + b;
      const int col = cg * 16 + i4 * 4;
      // broadcast h: write-through to LIC (coherent point), then history
      {
        short* hp = hbuf + p * (BATCH * HDIM) + bg * HDIM + col;
        int2_t hv2 = __builtin_bit_cast(int2_t, hv);
        asm volatile("global_store_dwordx2 %0, %1, off sc0 sc1"
                     :: "v"(hp), "v"(hv2) : "memory");
      }
      // drain all stores to visibility, then publish flag (own line, no RMW)
      asm volatile("s_waitcnt vmcnt(0)" ::: "memory");
      if (lane == 0)
        __hip_atomic_store(prodf, (unsigned)(t + 1), __ATOMIC_RELAXED,
                           __HIP_MEMORY_SCOPE_SYSTEM);
      // history write: write-through (keep L2 free of dirty vector lines)
      {
        short* hp2 = hs + ((t * BATCH) + bg) * HDIM + col;
        int2_t hv2 = __builtin_bit_cast(int2_t, hv);
        asm volatile("global_store_dwordx2 %0, %1, off sc0 sc1"
                     :: "v"(hp2), "v"(hv2) : "memory");
      }
    }
  }
}

// ---------------------------------------------------------------------------
// output projection: out[m][c] = sum_k hs[m][k]*fco[c][k] + bias[c]
// M=32768 (t*64+b), N=257 (padded 272), K=1024. A-frags in regs, B from global.
// grid: 512 x 256 (each WG: 64 rows; wave w -> m-tile w)
// ---------------------------------------------------------------------------
__global__ __launch_bounds__(256, 2) void outproj_kernel(
    const short* __restrict__ hs,
    const short* __restrict__ fcob,
    const float* __restrict__ fco_bias,
    float* __restrict__ out)
{
  const int tid = threadIdx.x, lane = tid & 63, w = tid >> 6;
  const int quad = lane >> 4, lm = lane & 15;
  const int blk = blockIdx.x;

  short8 afr[32];
  const short* ar = hs + (blk * 64 + w * 16 + lm) * HDIM;
#pragma unroll
  for (int kt = 0; kt < 32; ++kt)
    afr[kt] = *(const short8*)(ar + kt * 32 + quad * 8);

  for (int nt = 0; nt < 17; ++nt) {
    float4_t a0 = (float4_t){0.f,0.f,0.f,0.f}, a1 = (float4_t){0.f,0.f,0.f,0.f};
    const short* br = fcob + (nt * 16 + lm) * HDIM + quad * 8;
#pragma unroll
    for (int kt = 0; kt < 32; kt += 2) {
      short8 b0 = *(const short8*)(br + kt * 32);
      a0 = __builtin_amdgcn_mfma_f32_16x16x32_bf16(afr[kt], b0, a0, 0, 0, 0);
      short8 b1 = *(const short8*)(br + (kt + 1) * 32);
      a1 = __builtin_amdgcn_mfma_f32_16x16x32_bf16(afr[kt + 1], b1, a1, 0, 0, 0);
    }
    const int c = nt * 16 + lm;
    if (c < CDIM) {
      const float bias = fco_bias[c];
      const int mb = blk * 64 + w * 16 + quad * 4;
#pragma unroll
      for (int r = 0; r < 4; ++r)
        out[(mb + r) * CDIM + c] = a0[r] + a1[r] + bias;
    }
  }
}

// ---------------------------------------------------------------------------
extern "C" void kernel_launch(void* const* d_in, const int* in_sizes, int n_in,
                              void* d_out, int out_size, void* d_ws, size_t ws_size,
                              hipStream_t stream) {
  (void)in_sizes; (void)n_in; (void)out_size; (void)ws_size;
  const float* x     = (const float*)d_in[0];
  const float* wfx_w = (const float*)d_in[1];
  const float* wfx_b = (const float*)d_in[2];
  const float* wix_w = (const float*)d_in[3];
  const float* wix_b = (const float*)d_in[4];
  const float* wox_w = (const float*)d_in[5];
  const float* wox_b = (const float*)d_in[6];
  const float* wcx_w = (const float*)d_in[7];
  const float* wcx_b = (const float*)d_in[8];
  const float* wfh_w = (const float*)d_in[9];
  const float* wih_w = (const float*)d_in[10];
  const float* woh_w = (const float*)d_in[11];
  const float* wch_w = (const float*)d_in[12];
  const float* fco_w = (const float*)d_in[13];
  const float* fco_b = (const float*)d_in[14];
  float* out = (float*)d_out;

  char* ws = (char*)d_ws;
  short*    hs   = (short*)(ws);                                   // 67,108,864 B
  short*    fcob = (short*)(ws + 67108864);                        //    557,056 B
  short*    hbuf = (short*)(ws + 67108864 + 557056);               //    262,144 B
  unsigned* flg  = (unsigned*)(ws + 67108864 + 557056 + 262144);   //     16,384 B

  prep_kernel<<<272, 256, 0, stream>>>(fco_w, fcob, hbuf, flg);
  lstm_kernel<<<256, 256, 0, stream>>>(x,
                                       wfx_w, wix_w, wox_w, wcx_w,
                                       wfx_b, wix_b, wox_b, wcx_b,
                                       wfh_w, wih_w, woh_w, wch_w,
                                       hs, hbuf, flg);
  outproj_kernel<<<512, 256, 0, stream>>>(hs, fcob, fco_b, out);
}

// Round 6
// 2591.885 us; speedup vs baseline: 1.7073x; 1.7073x over previous
//
#include <hip/hip_runtime.h>

#define T_STEPS 512
#define BATCH 64
#define FDIM 256
#define HDIM 1024
#define CDIM 257

typedef __attribute__((ext_vector_type(8))) short short8;
typedef __attribute__((ext_vector_type(4))) short short4_t;
typedef __attribute__((ext_vector_type(4))) float float4_t;
typedef __attribute__((ext_vector_type(2))) int int2_t;

__device__ __forceinline__ short f2bf(float f) {
  unsigned u = __builtin_bit_cast(unsigned, f);
  unsigned r = (u + 0x7fffu + ((u >> 16) & 1u)) >> 16;   // RNE
  return (short)(r & 0xffffu);
}

__device__ __forceinline__ float sigmoid_f(float x) {
  return 1.0f / (1.0f + __expf(-x));
}
__device__ __forceinline__ float tanh_f(float x) {
  float s = __expf(-2.0f * fabsf(x));
  float t = (1.0f - s) / (1.0f + s);
  return (x < 0.0f) ? -t : t;
}

// ---------------------------------------------------------------------------
// prep: fco fp32 -> bf16 (padded to 272 rows), zero h double-buffer + flags
// grid: 272 x 256  (identical to the proven round-0 kernel)
// ---------------------------------------------------------------------------
__global__ void prep_kernel(const float* __restrict__ fco_w,
                            short* __restrict__ fcob,
                            short* __restrict__ hbuf,
                            unsigned* __restrict__ flg)
{
  const int tid = blockIdx.x * 256 + threadIdx.x;
  {
    const int idx = tid * 4;
    const int c = idx >> 10, k = idx & 1023;
    short4_t o;
    if (c < CDIM) {
      const float4_t f = *(const float4_t*)(fco_w + c * HDIM + k);
      o[0] = f2bf(f[0]); o[1] = f2bf(f[1]); o[2] = f2bf(f[2]); o[3] = f2bf(f[3]);
    } else {
      o[0] = 0; o[1] = 0; o[2] = 0; o[3] = 0;
    }
    *(short4_t*)(fcob + idx) = o;
  }
  if (tid < 16384) {   // 2*64*1024 shorts / 8
    short8 z = (short8){0,0,0,0,0,0,0,0};
    *(short8*)(hbuf + tid * 8) = z;
  }
  if (tid < 4096) flg[tid] = 0;   // 256 flag lines x 16 dwords
}

// ---------------------------------------------------------------------------
// persistent LSTM kernel: 128 WGs x 512 threads (8 waves).
// Role: (bq = blockIdx&3  -> 16 batch rows, XCD-affine under round-robin;
//        rank = blockIdx>>2 -> 32 h-cols as 2 tiles of 16).
// Wave w: tile = w>>2, K-chunk kc = w&3. Weights register-resident (A-frags).
//
// Protocol = round-0 proven, verbatim semantics: h broadcast write-through
// sc0 sc1 -> vmcnt(0) drain -> own-line monotone flag store (no RMW, no
// fence); consumers poll relaxed; h read with sc0 sc1 bypass loads.
// Geometry changes only WHO issues requests:
//   - ONE wave per WG polls (64 flags via 64 lanes), others wait at barrier
//   - h slice staged ONCE per WG into XOR-swizzled LDS; 8 waves read frags
//     from LDS  =>  h LIC traffic 8 MB/step -> 4 MB/step, polls halved.
// ---------------------------------------------------------------------------
__global__ __launch_bounds__(512, 2) void lstm_kernel(
    const float* __restrict__ x,
    const float* __restrict__ wfx, const float* __restrict__ wix,
    const float* __restrict__ wox, const float* __restrict__ wcx,
    const float* __restrict__ bfx, const float* __restrict__ bix,
    const float* __restrict__ box, const float* __restrict__ bcx,
    const float* __restrict__ wfh, const float* __restrict__ wih,
    const float* __restrict__ woh, const float* __restrict__ wch,
    short* __restrict__ hs, short* __restrict__ hbuf,
    unsigned* __restrict__ flg)
{
  // zbuf[tile][slot = kc*4+g][b(16) stride 20][i-quad 4]  fp32, 40 KiB
  __shared__ float zbuf[2][16 * 320];
  // staged h(t-1): 16 rows x 1024 bf16, rows XOR-swizzled (^ (row&7)<<4), 32 KiB
  __shared__ short hlds[16 * 1024];

  const int tid  = threadIdx.x;
  const int lane = tid & 63;
  const int w    = tid >> 6;          // 0..7
  const int kc   = w & 3;             // K-chunk (256 of 1024)
  const int tile = w >> 2;            // col tile (16 cols)
  const int quad = lane >> 4;
  const int lm   = lane & 15;
  const int bq   = blockIdx.x & 3;    // batch quarter (16 rows) — XCD-affine
  const int rank = blockIdx.x >> 2;   // 0..31, owns cols [rank*32, rank*32+32)
  const int cb   = rank * 32 + tile * 16;

  const float* Wh[4] = {wfh, wih, woh, wch};
  const float* Wx[4] = {wfx, wix, wox, wcx};
  const float* Bx[4] = {bfx, bix, box, bcx};

  // ---- preload weight A-fragments (bf16), K-split by wave ----
  short8 wr[4][8];   // recurrent: gate g, local k-tile (global kt = kc*8+ktl)
  short8 wxf[4][2];  // input proj: gate g, local k-tile (global kt2 = kc*2+ktl)
#pragma unroll
  for (int g = 0; g < 4; ++g) {
    const float* rw = Wh[g] + (cb + lm) * HDIM;
#pragma unroll
    for (int ktl = 0; ktl < 8; ++ktl) {
      const float* pk = rw + (kc * 8 + ktl) * 32 + quad * 8;
      short8 a;
#pragma unroll
      for (int j = 0; j < 8; ++j) a[j] = f2bf(pk[j]);
      wr[g][ktl] = a;
    }
    const float* rx = Wx[g] + (cb + lm) * FDIM;
#pragma unroll
    for (int ktl = 0; ktl < 2; ++ktl) {
      const float* pk = rx + (kc * 2 + ktl) * 32 + quad * 8;
      short8 a;
#pragma unroll
      for (int j = 0; j < 8; ++j) a[j] = f2bf(pk[j]);
      wxf[g][ktl] = a;
    }
  }

  // epilogue waves: w==3 -> tile0, w==7 -> tile1. 4 cells/lane (16x16).
  const int etile = (w == 7) ? 1 : 0;
  const int eb = lane & 15, ei4 = lane >> 4;
  const int ecol = rank * 32 + etile * 16 + ei4 * 4;
  float4_t biasv[4];
  float cst[4] = {0.f, 0.f, 0.f, 0.f};
#pragma unroll
  for (int g = 0; g < 4; ++g) {
#pragma unroll
    for (int r = 0; r < 4; ++r)
      biasv[g][r] = Bx[g][ecol + r];
  }

  // flags: one 64B line per (bq, rank, tile). Poller (wave0): lane L ->
  // line (rank=L>>1, tile=L&1). Producers: own line, monotone store.
  const unsigned* myf = flg + ((bq * 32 + (lane >> 1)) * 2 + (lane & 1)) * 16;
  unsigned* pf        = flg + ((bq * 32 + rank) * 2 + etile) * 16;

  for (int t = 0; t < T_STEPS; ++t) {
    const int p = t & 1;

    // ---- x projection: fully off the critical path (no h dependency) ----
    float4_t xf[2][2];
    {
      const float* xb = x + ((t * BATCH) + bq * 16 + lm) * FDIM;
#pragma unroll
      for (int i = 0; i < 2; ++i) {
        const float* pk = xb + (kc * 2 + i) * 32 + quad * 8;
        xf[i][0] = *(const float4_t*)(pk);
        xf[i][1] = *(const float4_t*)(pk + 4);
      }
    }
    short8 bx[2];
#pragma unroll
    for (int i = 0; i < 2; ++i) {
      short8 a;
      a[0] = f2bf(xf[i][0][0]); a[1] = f2bf(xf[i][0][1]);
      a[2] = f2bf(xf[i][0][2]); a[3] = f2bf(xf[i][0][3]);
      a[4] = f2bf(xf[i][1][0]); a[5] = f2bf(xf[i][1][1]);
      a[6] = f2bf(xf[i][1][2]); a[7] = f2bf(xf[i][1][3]);
      bx[i] = a;
    }
    float4_t acc[4];
#pragma unroll
    for (int g = 0; g < 4; ++g) acc[g] = (float4_t){0.f, 0.f, 0.f, 0.f};
#pragma unroll
    for (int i = 0; i < 2; ++i) {
#pragma unroll
      for (int g = 0; g < 4; ++g)
        acc[g] = __builtin_amdgcn_mfma_f32_16x16x32_bf16(wxf[g][i], bx[i], acc[g], 0, 0, 0);
    }

    // ---- wave0 polls all 64 producer-tile flags of this bq ----
    if (w == 0) {
      const unsigned want = (unsigned)t;
      unsigned v;
      do {
        v = __hip_atomic_load(myf, __ATOMIC_RELAXED, __HIP_MEMORY_SCOPE_SYSTEM);
      } while (__all((int)(v >= want)) == 0);
    }
    __syncthreads();   // B0: flags observed -> safe to read h(t-1)

    // ---- stage h(t-1) once per WG: 32 KB sc0sc1 loads -> swizzled LDS ----
    {
      const int row = tid >> 5;      // 0..15
      const int seg = tid & 31;      // 0..31 (64B segment)
      const short* src = hbuf + (p ^ 1) * (BATCH * HDIM)
                              + (bq * 16 + row) * HDIM + seg * 32;
      float4_t a0, a1, a2, a3;
      asm volatile(
        "global_load_dwordx4 %0, %4, off sc0 sc1\n\t"
        "global_load_dwordx4 %1, %4, off offset:16 sc0 sc1\n\t"
        "global_load_dwordx4 %2, %4, off offset:32 sc0 sc1\n\t"
        "global_load_dwordx4 %3, %4, off offset:48 sc0 sc1\n\t"
        "s_waitcnt vmcnt(0)"
        : "=&v"(a0), "=&v"(a1), "=&v"(a2), "=&v"(a3)
        : "v"(src)
        : "memory");
      const int bbase = row * 2048 + seg * 64;
      const int sw = (row & 7) << 4;
      *(short8*)((char*)hlds + ((bbase +  0) ^ sw)) = __builtin_bit_cast(short8, a0);
      *(short8*)((char*)hlds + ((bbase + 16) ^ sw)) = __builtin_bit_cast(short8, a1);
      *(short8*)((char*)hlds + ((bbase + 32) ^ sw)) = __builtin_bit_cast(short8, a2);
      *(short8*)((char*)hlds + ((bbase + 48) ^ sw)) = __builtin_bit_cast(short8, a3);
    }
    __syncthreads();   // B1: h(t-1) staged

    // ---- recurrent MFMAs: B-frags from swizzled LDS ----
    {
      const int hrow = lm * 2048;
      const int hcol = kc * 512 + quad * 16;
      const int hsw  = (lm & 7) << 4;
#pragma unroll
      for (int half = 0; half < 2; ++half) {
        short8 b0 = *(const short8*)((const char*)hlds + ((hrow + hcol + (half*4+0)*64) ^ hsw));
        short8 b1 = *(const short8*)((const char*)hlds + ((hrow + hcol + (half*4+1)*64) ^ hsw));
        short8 b2 = *(const short8*)((const char*)hlds + ((hrow + hcol + (half*4+2)*64) ^ hsw));
        short8 b3 = *(const short8*)((const char*)hlds + ((hrow + hcol + (half*4+3)*64) ^ hsw));
#pragma unroll
        for (int g = 0; g < 4; ++g) {
          acc[g] = __builtin_amdgcn_mfma_f32_16x16x32_bf16(wr[g][half*4+0], b0, acc[g], 0, 0, 0);
          acc[g] = __builtin_amdgcn_mfma_f32_16x16x32_bf16(wr[g][half*4+1], b1, acc[g], 0, 0, 0);
          acc[g] = __builtin_amdgcn_mfma_f32_16x16x32_bf16(wr[g][half*4+2], b2, acc[g], 0, 0, 0);
          acc[g] = __builtin_amdgcn_mfma_f32_16x16x32_bf16(wr[g][half*4+3], b3, acc[g], 0, 0, 0);
        }
      }
    }

    // partial z (K-chunk) -> LDS. rows = quad*4+r (i), cols = lm (b).
#pragma unroll
    for (int g = 0; g < 4; ++g)
      *(float4_t*)(&zbuf[tile][(kc * 4 + g) * 320 + lm * 20 + quad * 4]) = acc[g];

    __syncthreads();   // B2: z complete; epilogue reads protected from next
                       // step's z-writes by B0/B1 of step t+1

    if (w == 3 || w == 7) {
      const float* zb = &zbuf[etile][eb * 20 + ei4 * 4];
      float4_t zs[4];
#pragma unroll
      for (int g = 0; g < 4; ++g) {
        float4_t v0 = *(const float4_t*)(zb + (0  + g) * 320);
        float4_t v1 = *(const float4_t*)(zb + (4  + g) * 320);
        float4_t v2 = *(const float4_t*)(zb + (8  + g) * 320);
        float4_t v3 = *(const float4_t*)(zb + (12 + g) * 320);
        zs[g] = (v0 + v1) + (v2 + v3) + biasv[g];
      }
      short4_t hv;
#pragma unroll
      for (int r = 0; r < 4; ++r) {
        float ff = sigmoid_f(zs[0][r]);
        float ii = sigmoid_f(zs[1][r]);
        float oo = sigmoid_f(zs[2][r]);
        float aa = tanh_f(zs[3][r]);
        float cn = ii * aa + ff * cst[r];
        cst[r] = cn;
        hv[r] = f2bf(oo * tanh_f(cn));
      }
      const int bg = bq * 16 + eb;
      // broadcast h: write-through to LIC (coherent point)
      {
        short* hp = hbuf + p * (BATCH * HDIM) + bg * HDIM + ecol;
        int2_t hv2 = __builtin_bit_cast(int2_t, hv);
        asm volatile("global_store_dwordx2 %0, %1, off sc0 sc1"
                     :: "v"(hp), "v"(hv2) : "memory");
      }
      // drain to visibility, then publish flag (own line, monotone, no RMW)
      asm volatile("s_waitcnt vmcnt(0)" ::: "memory");
      if (lane == 0)
        __hip_atomic_store(pf, (unsigned)(t + 1), __ATOMIC_RELAXED,
                           __HIP_MEMORY_SCOPE_SYSTEM);
      // history write: off the critical path
      *(short4_t*)(hs + ((t * BATCH) + bg) * HDIM + ecol) = hv;
    }
  }
}

// ---------------------------------------------------------------------------
// output projection: out[m][c] = sum_k hs[m][k]*fco[c][k] + bias[c]
// M=32768 (t*64+b), N=257 (padded 272), K=1024. A-frags in regs, B from global.
// grid: 512 x 256 (each WG: 64 rows; wave w -> m-tile w)
// ---------------------------------------------------------------------------
__global__ __launch_bounds__(256, 2) void outproj_kernel(
    const short* __restrict__ hs,
    const short* __restrict__ fcob,
    const float* __restrict__ fco_bias,
    float* __restrict__ out)
{
  const int tid = threadIdx.x, lane = tid & 63, w = tid >> 6;
  const int quad = lane >> 4, lm = lane & 15;
  const int blk = blockIdx.x;

  short8 afr[32];
  const short* ar = hs + (blk * 64 + w * 16 + lm) * HDIM;
#pragma unroll
  for (int kt = 0; kt < 32; ++kt)
    afr[kt] = *(const short8*)(ar + kt * 32 + quad * 8);

  for (int nt = 0; nt < 17; ++nt) {
    float4_t a0 = (float4_t){0.f,0.f,0.f,0.f}, a1 = (float4_t){0.f,0.f,0.f,0.f};
    const short* br = fcob + (nt * 16 + lm) * HDIM + quad * 8;
#pragma unroll
    for (int kt = 0; kt < 32; kt += 2) {
      short8 b0 = *(const short8*)(br + kt * 32);
      a0 = __builtin_amdgcn_mfma_f32_16x16x32_bf16(afr[kt], b0, a0, 0, 0, 0);
      short8 b1 = *(const short8*)(br + (kt + 1) * 32);
      a1 = __builtin_amdgcn_mfma_f32_16x16x32_bf16(afr[kt + 1], b1, a1, 0, 0, 0);
    }
    const int c = nt * 16 + lm;
    if (c < CDIM) {
      const float bias = fco_bias[c];
      const int mb = blk * 64 + w * 16 + quad * 4;
#pragma unroll
      for (int r = 0; r < 4; ++r)
        out[(mb + r) * CDIM + c] = a0[r] + a1[r] + bias;
    }
  }
}

// ---------------------------------------------------------------------------
extern "C" void kernel_launch(void* const* d_in, const int* in_sizes, int n_in,
                              void* d_out, int out_size, void* d_ws, size_t ws_size,
                              hipStream_t stream) {
  (void)in_sizes; (void)n_in; (void)out_size; (void)ws_size;
  const float* x     = (const float*)d_in[0];
  const float* wfx_w = (const float*)d_in[1];
  const float* wfx_b = (const float*)d_in[2];
  const float* wix_w = (const float*)d_in[3];
  const float* wix_b = (const float*)d_in[4];
  const float* wox_w = (const float*)d_in[5];
  const float* wox_b = (const float*)d_in[6];
  const float* wcx_w = (const float*)d_in[7];
  const float* wcx_b = (const float*)d_in[8];
  const float* wfh_w = (const float*)d_in[9];
  const float* wih_w = (const float*)d_in[10];
  const float* woh_w = (const float*)d_in[11];
  const float* wch_w = (const float*)d_in[12];
  const float* fco_w = (const float*)d_in[13];
  const float* fco_b = (const float*)d_in[14];
  float* out = (float*)d_out;

  char* ws = (char*)d_ws;
  short*    hs   = (short*)(ws);                                   // 67,108,864 B
  short*    fcob = (short*)(ws + 67108864);                        //    557,056 B
  short*    hbuf = (short*)(ws + 67108864 + 557056);               //    262,144 B
  unsigned* flg  = (unsigned*)(ws + 67108864 + 557056 + 262144);   //     16,384 B

  prep_kernel<<<272, 256, 0, stream>>>(fco_w, fcob, hbuf, flg);
  lstm_kernel<<<128, 512, 0, stream>>>(x,
                                       wfx_w, wix_w, wox_w, wcx_w,
                                       wfx_b, wix_b, wox_b, wcx_b,
                                       wfh_w, wih_w, woh_w, wch_w,
                                       hs, hbuf, flg);
  outproj_kernel<<<512, 256, 0, stream>>>(hs, fcob, fco_b, out);
}